// Round 16
// baseline (61.411 us; speedup 1.0000x reference)
//
#include <hip/hip_runtime.h>
#include <hip/hip_fp16.h>

// NCC (local normalized cross-correlation) loss, win=9^3, SAME zero padding.
// Volume: (B=2, C=1, D=160, H=192, W=160) fp32. Output: scalar fp32 loss.
//
// v13: wave-local phase fusion — 4 barriers -> 2 barriers + 2 lgkm fences.
//  - Cross-round invariant: per-step wall ~1940 cyc at ~3.4 resident
//    blocks/CU regardless of grid/LDS/barrier-count tweaks; the serial
//    phase chain is the binder. Shorten it by making producer==consumer
//    at wave granularity:
//      * P1->P2: each wave owns 6 halo rows; z-sums go to a WAVE-PRIVATE
//        Zq region, read back by the same wave's P2 -> lgkmcnt(0) only.
//      * P3->P4: wave w computes the Sq quarter (rows 4w..4w+3) its own
//        P4 lanes read -> lgkmcnt(0) only. Sq aliases the dead private Zq.
//      * Rq stays cross-wave: 2 s_barriers/step (P2w->P3r, P3r->P2w WAR).
//  - P0 slide refactor: S2 += (a-s)(a+s) via fma; 16 -> 11 f4-ops.
//  - Else v12: fp16 LDS staging, fp32 z-slide/cc, lgkm-only barriers
//    (prefetch survives), float4 loads + full-step prefetch, ZC=5,
//    3840 blocks, XCD swizzle, deterministic two-stage reduction.

#define NX 160
#define NY 192
#define NZ 160
#define NB 2
#define SLICE (NX * NY)            // 30720
#define VOL   (SLICE * NZ)         // 4915200
#define TOTAL (VOL * NB)           // 9830400

#define TX 32
#define TY 16
#define ZC 5
#define GXT (NX / TX)              // 5
#define GYT (NY / TY)              // 12
#define GZT (NZ / ZC)              // 32
#define NBLK (GXT * GYT * GZT * NB) // 3840

#define WROWS 6                    // halo rows per wave (24 total)
#define ZQS 48                     // private Zq row stride (halfs), 96B
#define ZQP (WROWS * ZQS + 8)      // 296 halfs per q-plane (wave-local)
#define ZPRIV (5 * ZQP)            // 1480
#define ZPRIVP 1504                // padded private region (3008 B)
#define SQS 40                     // Sq row stride (halfs) inside private alias
#define SQP (4 * SQS + 8)          // 168 halfs per q (4 rows)
#define RRS 40                     // Rq row stride (halfs), 80B
#define RQQ (24 * RRS + 8)         // 968
#define INV729 (1.0f / 729.0f)

__device__ __forceinline__ void lds_barrier() {
    // Block barrier WITHOUT vmcnt drain: prefetched global loads stay in
    // flight (hipcc's __syncthreads would emit s_waitcnt vmcnt(0)).
    asm volatile("s_waitcnt lgkmcnt(0)" ::: "memory");
    __builtin_amdgcn_s_barrier();
}
__device__ __forceinline__ void lds_fence() {
    // Same-wave LDS visibility only (wave64 lockstep): no s_barrier.
    asm volatile("s_waitcnt lgkmcnt(0)" ::: "memory");
}

__device__ __forceinline__ float4 f4add(float4 a, float4 b) {
    return make_float4(a.x + b.x, a.y + b.y, a.z + b.z, a.w + b.w);
}
__device__ __forceinline__ float4 f4sub(float4 a, float4 b) {
    return make_float4(a.x - b.x, a.y - b.y, a.z - b.z, a.w - b.w);
}
__device__ __forceinline__ float4 f4mul(float4 a, float4 b) {
    return make_float4(a.x * b.x, a.y * b.y, a.z * b.z, a.w * b.w);
}
__device__ __forceinline__ float4 f4fma(float4 a, float4 b, float4 c) {
    return make_float4(fmaf(a.x, b.x, c.x), fmaf(a.y, b.y, c.y),
                       fmaf(a.z, b.z, c.z), fmaf(a.w, b.w, c.w));
}

union U8 { uint4 u; __half2 h[4]; };   // 8 fp16 = one b128
__device__ __forceinline__ U8 ld8(const __half* p) {
    U8 r; r.u = *(const uint4*)p; return r;
}
__device__ __forceinline__ void st8(__half* p, const U8& v) {
    *(uint4*)p = v.u;
}

__global__ __launch_bounds__(256) void ncc_main(
    const float* __restrict__ J_pred,   // predict
    const float* __restrict__ I_targ,   // target
    float* __restrict__ partial)
{
    const int tid  = threadIdx.x;
    const int wave = tid >> 6;
    const int lane = tid & 63;

    // XCD-chunked swizzle: 8 XCDs x 480 consecutive logical blocks (bijective).
    const int lin = blockIdx.x;
    const int s   = (lin & 7) * (NBLK / 8) + (lin >> 3);
    const int bx  = s % GXT;
    const int r1  = s / GXT;
    const int by  = r1 % GYT;
    const int r2  = r1 / GYT;
    const int zc  = r2 % GZT;
    const int b   = r2 / GZT;

    const int x0 = bx * TX;
    const int y0 = by * TY;
    const int z0 = zc * ZC;

    __shared__ __align__(16) __half ZS[4 * ZPRIVP];  // 12032 B (private Zq / Sq alias)
    __shared__ __align__(16) __half Rq[5 * RQQ];     //  9680 B (shared x-sums)
    __shared__ float redbuf[4];
    __half* const ZW = &ZS[wave * ZPRIVP];           // this wave's private region

    // ---- column ownership: 60 lanes/wave, 6 rows x 10 float4-groups ----
    const bool is_col = (lane < 60);
    const int  rl  = lane / 10;            // row within wave (0..5)
    const int  xg  = lane - rl * 10;       // float4 group (0..9)
    const int  row = wave * WROWS + rl;    // halo row (0..23)
    const int  gy  = y0 - 4 + row;
    const int  gx  = x0 - 4 + xg * 4;      // 4-aligned; fully valid or fully OOB
    const bool vxy = is_col && ((unsigned)gy < (unsigned)NY) && (gx >= 0) && (gx <= NX - 4);
    const size_t cbase = (size_t)b * VOL + (vxy ? (size_t)(gy * NX + gx) : 0);
    const float* const baseI = I_targ + cbase;
    const float* const baseJ = J_pred + cbase;

    // ---- running z-box-sums over 4 owned columns (fp32, exact sliding) ----
    const float4 f40 = make_float4(0.f, 0.f, 0.f, 0.f);
    float4 rS0 = f40, rS1 = f40, rS2 = f40, rS3 = f40, rS4 = f40;

    // warmup: add slices z0-5 .. z0+3 (9 slices; OOB z -> zeros). Main loop
    // always subtracts z0+so-5; at so=0 that removes the z0-5 slice added
    // here (cancellation exact: absmax 0.0 in v2-v12 with this scheme).
#pragma unroll 3
    for (int ss = 0; ss < 9; ++ss) {
        const int z = z0 - 5 + ss;
        float4 aI = f40, aJ = f40;
        if (vxy && (unsigned)z < (unsigned)NZ) {
            aI = *(const float4*)(baseI + (size_t)z * SLICE);
            aJ = *(const float4*)(baseJ + (size_t)z * SLICE);
        }
        rS0 = f4add(rS0, aI);
        rS1 = f4add(rS1, aJ);
        rS2 = f4fma(aI, aI, rS2);
        rS3 = f4fma(aJ, aJ, rS3);
        rS4 = f4fma(aI, aJ, rS4);
    }

    // pending (prefetched) slices for so = 0
    float4 nIa = f40, nJa = f40, nIs = f40, nJs = f40;
    if (vxy) {
        const int za = z0 + 4;                 // always < NZ
        nIa = *(const float4*)(baseI + (size_t)za * SLICE);
        nJa = *(const float4*)(baseJ + (size_t)za * SLICE);
        const int zs = z0 - 5;
        if (zs >= 0) {
            nIs = *(const float4*)(baseI + (size_t)zs * SLICE);
            nJs = *(const float4*)(baseJ + (size_t)zs * SLICE);
        }
    }

    const int ty  = tid >> 4;      // 0..15 (output row; quarter = wave)
    const int tx2 = tid & 15;      // x-pair index (2 voxels/thread)
    float acc = 0.f;

#pragma unroll 1
    for (int so = 0; so < ZC; ++so) {
        // P0: consume pending slices; slide z-window via d/p factoring
        {
            const float4 dI = f4sub(nIa, nIs), pI = f4add(nIa, nIs);
            const float4 dJ = f4sub(nJa, nJs), pJ = f4add(nJa, nJs);
            rS0 = f4add(rS0, dI);
            rS1 = f4add(rS1, dJ);
            rS2 = f4fma(dI, pI, rS2);
            rS3 = f4fma(dJ, pJ, rS3);
            rS4 = f4add(rS4, f4sub(f4mul(nIa, nJa), f4mul(nIs, nJs)));
        }

        // issue next step's loads NOW — they stay in flight across both
        // lgkm-only barriers and are consumed at the next P0.
        nIa = f40; nJa = f40; nIs = f40; nJs = f40;
        if (so < ZC - 1 && vxy) {
            const int za = z0 + 5 + so;
            if (za < NZ) {
                nIa = *(const float4*)(baseI + (size_t)za * SLICE);
                nJa = *(const float4*)(baseJ + (size_t)za * SLICE);
            }
            const int zs = z0 + so - 4;
            if (zs >= 0) {   // zs <= z0+ZC-2 < NZ always
                nIs = *(const float4*)(baseI + (size_t)zs * SLICE);
                nJs = *(const float4*)(baseJ + (size_t)zs * SLICE);
            }
        }

        // P1: stage z-sums as fp16 into WAVE-PRIVATE Zq (b64 per quantity)
        if (is_col) {
            const int o = rl * ZQS + xg * 4;
            union { uint2 u; __half2 h[2]; } pk;
            pk.h[0] = __float22half2_rn(make_float2(rS0.x, rS0.y));
            pk.h[1] = __float22half2_rn(make_float2(rS0.z, rS0.w));
            *(uint2*)&ZW[0 * ZQP + o] = pk.u;
            pk.h[0] = __float22half2_rn(make_float2(rS1.x, rS1.y));
            pk.h[1] = __float22half2_rn(make_float2(rS1.z, rS1.w));
            *(uint2*)&ZW[1 * ZQP + o] = pk.u;
            pk.h[0] = __float22half2_rn(make_float2(rS2.x, rS2.y));
            pk.h[1] = __float22half2_rn(make_float2(rS2.z, rS2.w));
            *(uint2*)&ZW[2 * ZQP + o] = pk.u;
            pk.h[0] = __float22half2_rn(make_float2(rS3.x, rS3.y));
            pk.h[1] = __float22half2_rn(make_float2(rS3.z, rS3.w));
            *(uint2*)&ZW[3 * ZQP + o] = pk.u;
            pk.h[0] = __float22half2_rn(make_float2(rS4.x, rS4.y));
            pk.h[1] = __float22half2_rn(make_float2(rS4.z, rS4.w));
            *(uint2*)&ZW[4 * ZQP + o] = pk.u;
        }
        lds_fence();   // same-wave producer->consumer: no s_barrier needed

        // P2: x-boxsum, 60 tasks/wave = 6 own rows x 5 q x 2 halves.
        // Read 24 fp16 (3 b128) from private Zq, slide 16 in fp32,
        // write 2 b128 to SHARED Rq at the global row.
        if (lane < 60) {
            const int rem = lane - rl * 10;       // 0..9
            const int q   = rem >> 1;
            const int h   = rem & 1;
            const __half* src = &ZW[q * ZQP + rl * ZQS + h * 16];
            float c[24];
#pragma unroll
            for (int g = 0; g < 3; ++g) {
                U8 v = ld8(src + g * 8);
#pragma unroll
                for (int j = 0; j < 4; ++j) {
                    const float2 f = __half22float2(v.h[j]);
                    c[g * 8 + j * 2 + 0] = f.x;
                    c[g * 8 + j * 2 + 1] = f.y;
                }
            }
            float sx = c[0] + c[1] + c[2] + c[3] + c[4]
                     + c[5] + c[6] + c[7] + c[8];
            float o[16];
            o[0] = sx;
#pragma unroll
            for (int i = 1; i < 16; ++i) { sx += c[i + 8] - c[i - 1]; o[i] = sx; }
            __half* dst = &Rq[q * RQQ + row * RRS + h * 16];
#pragma unroll
            for (int g = 0; g < 2; ++g) {
                U8 w;
#pragma unroll
                for (int j = 0; j < 4; ++j)
                    w.h[j] = __float22half2_rn(make_float2(o[g * 8 + j * 2],
                                                           o[g * 8 + j * 2 + 1]));
                st8(dst + g * 8, w);
            }
        }
        lds_barrier();   // A: Rq(t) fully written (cross-wave)

        // P3: y-boxsum, 20 tasks/wave = 5 q x 4 x-groups(8 wide); wave w
        // computes Sq quarter w (output rows 4w..4w+3) into its PRIVATE
        // alias (Zq dead after own P2). Packed fp16 slide, no cvt.
        if (lane < 20) {
            const int q3 = lane >> 2;            // quantity
            const int x3 = lane & 3;             // x-group (8 wide)
            const __half* rb = &Rq[q3 * RQQ + (wave * 4) * RRS + x3 * 8];
            __half* sb = &ZW[q3 * SQP + x3 * 8];
            U8 sum = ld8(rb);
#pragma unroll
            for (int k = 1; k < 9; ++k) {
                const U8 t = ld8(rb + k * RRS);
#pragma unroll
                for (int j = 0; j < 4; ++j) sum.h[j] = __hadd2(sum.h[j], t.h[j]);
            }
            st8(sb, sum);
#pragma unroll
            for (int i = 1; i < 4; ++i) {
                const U8 nw = ld8(rb + (i + 8) * RRS);
                const U8 od = ld8(rb + (i - 1) * RRS);
#pragma unroll
                for (int j = 0; j < 4; ++j)
                    sum.h[j] = __hadd2(sum.h[j], __hsub2(nw.h[j], od.h[j]));
                st8(sb + i * SQS, sum);
            }
        }
        lds_fence();   // same-wave producer->consumer: no s_barrier needed

        // P4: cc for 2 voxels per thread (reads own wave's Sq quarter)
        {
            const int o = (ty & 3) * SQS + tx2 * 2;
            const float2 S0 = __half22float2(*(const __half2*)&ZW[0 * SQP + o]);
            const float2 S1 = __half22float2(*(const __half2*)&ZW[1 * SQP + o]);
            const float2 S2 = __half22float2(*(const __half2*)&ZW[2 * SQP + o]);
            const float2 S3 = __half22float2(*(const __half2*)&ZW[3 * SQP + o]);
            const float2 S4 = __half22float2(*(const __half2*)&ZW[4 * SQP + o]);
            {
                const float cross = S4.x - S0.x * S1.x * INV729;
                const float Iv    = S2.x - S0.x * S0.x * INV729;
                const float Jv    = S3.x - S1.x * S1.x * INV729;
                acc += (cross * cross) / (Iv * Jv + 1e-5f);
            }
            {
                const float cross = S4.y - S0.y * S1.y * INV729;
                const float Iv    = S2.y - S0.y * S0.y * INV729;
                const float Jv    = S3.y - S1.y * S1.y * INV729;
                acc += (cross * cross) / (Iv * Jv + 1e-5f);
            }
        }
        lds_barrier();   // B: P3's Rq reads done before next step's P2 writes
        // (private ZW hazards — P1(t+1) vs P2(t) reads, P3(t+1) vs P4(t)
        //  reads — are same-wave, ordered by program order + fences.)
    }

    // ---- block reduction (deterministic within block) ----
#pragma unroll
    for (int off = 32; off > 0; off >>= 1) acc += __shfl_down(acc, off);
    __syncthreads();
    if ((tid & 63) == 0) redbuf[tid >> 6] = acc;
    __syncthreads();
    if (tid == 0) partial[s] = redbuf[0] + redbuf[1] + redbuf[2] + redbuf[3];
}

__global__ __launch_bounds__(256) void ncc_final(
    const float* __restrict__ partial, float* __restrict__ out)
{
    __shared__ float sm[256];
    const int tid = threadIdx.x;
    float v = 0.f;
    for (int i = tid; i < NBLK; i += 256) v += partial[i];
    sm[tid] = v;
    __syncthreads();
#pragma unroll
    for (int w = 128; w > 0; w >>= 1) {
        if (tid < w) sm[tid] += sm[tid + w];
        __syncthreads();
    }
    if (tid == 0) out[0] = 1.0f - sm[0] * (1.0f / (float)TOTAL);
}

extern "C" void kernel_launch(void* const* d_in, const int* in_sizes, int n_in,
                              void* d_out, int out_size, void* d_ws, size_t ws_size,
                              hipStream_t stream)
{
    const float* predict = (const float*)d_in[0];  // J
    const float* target  = (const float*)d_in[1];  // I
    float* partial = (float*)d_ws;                 // 3840 floats (15.4 KB)

    ncc_main<<<dim3(NBLK), 256, 0, stream>>>(predict, target, partial);
    ncc_final<<<1, 256, 0, stream>>>(partial, (float*)d_out);
}